// Round 2
// baseline (1397.581 us; speedup 1.0000x reference)
//
#include <hip/hip_runtime.h>
#include <math.h>

namespace {

constexpr int C_DIM  = 128;
constexpr int B_SZ   = 256;
constexpr int NP_OFF = 32768;         // np-graph node-id offset
constexpr int N_TOT  = 32896;         // 32768 + 128 combined rows
constexpr int E_P    = 524288;
constexpr int E_NP   = 2048;
constexpr int E_TOT  = E_P + E_NP;
constexpr int WALK   = 7;
constexpr int NTR    = 257;           // 256 p-block traces + 1 np trace

// ---------------- precompute ----------------

__global__ void init_kernel(int* __restrict__ cnt, float* __restrict__ tr) {
  int i = blockIdx.x * blockDim.x + threadIdx.x;
  if (i < N_TOT) cnt[i] = 0;
  if (i < WALK * NTR) tr[i] = 0.0f;
}

// NOTE: harness delivers integer inputs as int32 (even though reference uses int64)
__global__ void count_kernel(const int* __restrict__ ei_p,
                             const int* __restrict__ ei_np,
                             int* __restrict__ cnt) {
  int e = blockIdx.x * blockDim.x + threadIdx.x;
  if (e < E_P) {
    int d = ei_p[E_P + e];
    atomicAdd(&cnt[d], 1);
  } else if (e < E_TOT) {
    int i = e - E_P;
    int d = ei_np[E_NP + i] + NP_OFF;
    atomicAdd(&cnt[d], 1);
  }
}

__global__ void dinv_kernel(const int* __restrict__ cnt, float* __restrict__ dinv,
                            int* __restrict__ fill) {
  int i = blockIdx.x * blockDim.x + threadIdx.x;
  if (i < N_TOT) {
    dinv[i] = rsqrtf((float)cnt[i] + 1.0f);  // +1 self loop
    fill[i] = 0;
  }
}

// single-block hierarchical exclusive scan of cnt -> ptr (length N_TOT+1)
__global__ void scan_kernel(const int* __restrict__ cnt, int* __restrict__ ptr) {
  const int T = 1024;
  __shared__ int part[T];
  int tid = threadIdx.x;
  const int chunk = (N_TOT + T - 1) / T;
  int begin = tid * chunk;
  int end = begin + chunk;
  if (end > N_TOT) end = N_TOT;
  int s = 0;
  for (int i = begin; i < end; ++i) s += cnt[i];
  part[tid] = s;
  __syncthreads();
  for (int off = 1; off < T; off <<= 1) {
    int v = (tid >= off) ? part[tid - off] : 0;
    __syncthreads();
    part[tid] += v;
    __syncthreads();
  }
  if (tid == T - 1) ptr[N_TOT] = part[T - 1];
  int run = (tid == 0) ? 0 : part[tid - 1];
  for (int i = begin; i < end; ++i) { ptr[i] = run; run += cnt[i]; }
}

__global__ void fill_kernel(const int* __restrict__ ei_p,
                            const int* __restrict__ ei_np,
                            const int* __restrict__ ptr, int* __restrict__ fill,
                            const float* __restrict__ dinv,
                            int* __restrict__ csr_src, float* __restrict__ csr_norm) {
  int e = blockIdx.x * blockDim.x + threadIdx.x;
  int s, d;
  if (e < E_P) {
    s = ei_p[e];
    d = ei_p[E_P + e];
  } else if (e < E_TOT) {
    int i = e - E_P;
    s = ei_np[i] + NP_OFF;
    d = ei_np[E_NP + i] + NP_OFF;
  } else {
    return;
  }
  int pos = ptr[d] + atomicAdd(&fill[d], 1);
  csr_src[pos] = s;
  csr_norm[pos] = dinv[s] * dinv[d];
}

__global__ void concat_kernel(const float* __restrict__ x_p,
                              const float* __restrict__ x_np,
                              float* __restrict__ hA) {
  int i = blockIdx.x * blockDim.x + threadIdx.x;  // float4 index
  const int NP4 = NP_OFF * C_DIM / 4;
  const int NT4 = N_TOT * C_DIM / 4;
  if (i < NP4) {
    ((float4*)hA)[i] = ((const float4*)x_p)[i];
  } else if (i < NT4) {
    ((float4*)hA)[i] = ((const float4*)x_np)[i - NP4];
  }
}

// ---------------- per-step kernels ----------------

// xw[M x 128] = A[M x 128] @ W[128 x 128], fp32 (no fp32 MFMA on CDNA4)
// BM=64, BN=128, BK=16, 256 threads, 4x8 register tile per thread
constexpr int BM = 64;
constexpr int BK = 16;
constexpr int BN = 128;

__global__ __launch_bounds__(256) void gemm_kernel(const float* __restrict__ A,
                                                   const float* __restrict__ W,
                                                   float* __restrict__ Cm) {
  __shared__ float As[BK][BM];
  __shared__ float Bs[BK][BN];
  const int tid = threadIdx.x;
  const int row0 = blockIdx.x * BM;
  const int tx = tid & 15;        // n-tile index
  const int ty = tid >> 4;        // m-tile index
  const int m0 = ty * 4;
  const int n0 = tx * 8;
  const int a_row = tid >> 2;          // 0..63
  const int a_kc = (tid & 3) * 4;      // 0,4,8,12
  const int b_krow = tid >> 4;         // 0..15
  const int b_col = (tid & 15) * 8;    // 0..120

  float acc[4][8];
#pragma unroll
  for (int r = 0; r < 4; ++r)
#pragma unroll
    for (int c = 0; c < 8; ++c) acc[r][c] = 0.0f;

  for (int k0 = 0; k0 < C_DIM; k0 += BK) {
    float4 av = *(const float4*)&A[(size_t)(row0 + a_row) * C_DIM + k0 + a_kc];
    As[a_kc + 0][a_row] = av.x;
    As[a_kc + 1][a_row] = av.y;
    As[a_kc + 2][a_row] = av.z;
    As[a_kc + 3][a_row] = av.w;
    *(float4*)&Bs[b_krow][b_col] =
        *(const float4*)&W[(size_t)(k0 + b_krow) * C_DIM + b_col];
    *(float4*)&Bs[b_krow][b_col + 4] =
        *(const float4*)&W[(size_t)(k0 + b_krow) * C_DIM + b_col + 4];
    __syncthreads();
#pragma unroll
    for (int k = 0; k < BK; ++k) {
      float4 a4 = *(const float4*)&As[k][m0];
      float4 bL = *(const float4*)&Bs[k][n0];
      float4 bH = *(const float4*)&Bs[k][n0 + 4];
      float avr[4] = {a4.x, a4.y, a4.z, a4.w};
      float bvr[8] = {bL.x, bL.y, bL.z, bL.w, bH.x, bH.y, bH.z, bH.w};
#pragma unroll
      for (int r = 0; r < 4; ++r)
#pragma unroll
        for (int c = 0; c < 8; ++c) acc[r][c] += avr[r] * bvr[c];
    }
    __syncthreads();
  }

#pragma unroll
  for (int r = 0; r < 4; ++r) {
    float4 o0 = make_float4(acc[r][0], acc[r][1], acc[r][2], acc[r][3]);
    float4 o1 = make_float4(acc[r][4], acc[r][5], acc[r][6], acc[r][7]);
    *(float4*)&Cm[(size_t)(row0 + m0 + r) * C_DIM + n0] = o0;
    *(float4*)&Cm[(size_t)(row0 + m0 + r) * C_DIM + n0 + 4] = o1;
  }
}

// h_out[node][c] = b[c] + dinv[node]^2 * xw[node][c] + sum_e norm[e]*xw[src[e]][c]
// fused: diagonal thread accumulates into the per-step trace table.
__global__ __launch_bounds__(128) void agg_kernel(const float* __restrict__ xw,
                                                  float* __restrict__ hout,
                                                  const int* __restrict__ ptr,
                                                  const int* __restrict__ srcs,
                                                  const float* __restrict__ norms,
                                                  const float* __restrict__ dinv,
                                                  const float* __restrict__ bias,
                                                  float* __restrict__ tr, int step) {
  const int node = blockIdx.x;
  const int c = threadIdx.x;
  const float di = dinv[node];
  float acc = bias[c] + di * di * xw[(size_t)node * C_DIM + c];
  const int e0 = ptr[node];
  const int e1 = ptr[node + 1];
  for (int e = e0; e < e1; ++e) {
    int s = srcs[e];
    float nv = norms[e];
    acc += nv * xw[(size_t)s * C_DIM + c];
  }
  hout[(size_t)node * C_DIM + c] = acc;
  if (c == (node & 127)) {
    atomicAdd(&tr[step * NTR + (node >> 7)], acc);
  }
}

// ---------------- epilogue ----------------

__global__ __launch_bounds__(256) void final_kernel(const float* __restrict__ tr,
                                                    const float* __restrict__ y,
                                                    const float* __restrict__ W1,
                                                    const float* __restrict__ b1,
                                                    const float* __restrict__ W2,
                                                    const float* __restrict__ b2,
                                                    float* __restrict__ out) {
  __shared__ float sm[B_SZ];
  const int b = threadIdx.x;
  const float sgn = (y[b] - 0.5f) * 2.0f;
  float vals[WALK];
#pragma unroll
  for (int t = 0; t < WALK; ++t)
    vals[t] = (tr[t * NTR + b] - tr[t * NTR + 256]) * sgn;

  for (int t = 0; t < WALK; ++t) {
    sm[b] = vals[t];
    __syncthreads();
    for (int off = 128; off >= 1; off >>= 1) {
      if (b < off) sm[b] += sm[b + off];
      __syncthreads();
    }
    float mean = sm[0] * (1.0f / 256.0f);
    __syncthreads();
    float d = vals[t] - mean;
    sm[b] = d * d;
    __syncthreads();
    for (int off = 128; off >= 1; off >>= 1) {
      if (b < off) sm[b] += sm[b + off];
      __syncthreads();
    }
    float stdv = sqrtf(sm[0] * (1.0f / 255.0f));  // ddof=1
    __syncthreads();
    vals[t] = d / stdv;
  }

  float o = b2[0];
#pragma unroll
  for (int j = 0; j < 15; ++j) {
    float a = b1[j];
#pragma unroll
    for (int t = 0; t < WALK; ++t) a += vals[t] * W1[t * 15 + j];
    o += fmaxf(a, 0.0f) * W2[j];
  }
  out[b] = 1.0f / (1.0f + expf(-o));
}

}  // namespace

extern "C" void kernel_launch(void* const* d_in, const int* in_sizes, int n_in,
                              void* d_out, int out_size, void* d_ws, size_t ws_size,
                              hipStream_t stream) {
  const float* x_p   = (const float*)d_in[0];
  const float* x_np  = (const float*)d_in[1];
  const float* y     = (const float*)d_in[2];
  const int* ei_p    = (const int*)d_in[3];   // int inputs arrive as int32
  const int* ei_np   = (const int*)d_in[4];
  const float* W_gcn = (const float*)d_in[5];
  const float* b_gcn = (const float*)d_in[6];
  const float* W1    = (const float*)d_in[7];
  const float* b1    = (const float*)d_in[8];
  const float* W2    = (const float*)d_in[9];
  const float* b2    = (const float*)d_in[10];
  float* out         = (float*)d_out;

  // bump allocator over d_ws (re-poisoned to 0xAA each call; we init all we read)
  char* p = (char*)d_ws;
  auto alloc = [&](size_t bytes) -> void* {
    void* r = (void*)p;
    p += (bytes + 255) & ~(size_t)255;
    return r;
  };
  float* hA       = (float*)alloc((size_t)N_TOT * C_DIM * 4);  // h (in-place per step)
  float* xw       = (float*)alloc((size_t)N_TOT * C_DIM * 4);  // h @ W
  float* dinv     = (float*)alloc((size_t)N_TOT * 4);
  int*   cnt      = (int*)alloc((size_t)N_TOT * 4);
  int*   fill     = (int*)alloc((size_t)N_TOT * 4);
  int*   ptr      = (int*)alloc((size_t)(N_TOT + 1) * 4);
  int*   csr_src  = (int*)alloc((size_t)E_TOT * 4);
  float* csr_norm = (float*)alloc((size_t)E_TOT * 4);
  float* tr       = (float*)alloc((size_t)WALK * NTR * 4);

  // --- precompute: degrees, norms, CSR (edges invariant across the 7 steps) ---
  init_kernel<<<(N_TOT + 255) / 256, 256, 0, stream>>>(cnt, tr);
  count_kernel<<<(E_TOT + 255) / 256, 256, 0, stream>>>(ei_p, ei_np, cnt);
  dinv_kernel<<<(N_TOT + 255) / 256, 256, 0, stream>>>(cnt, dinv, fill);
  scan_kernel<<<1, 1024, 0, stream>>>(cnt, ptr);
  fill_kernel<<<(E_TOT + 255) / 256, 256, 0, stream>>>(ei_p, ei_np, ptr, fill, dinv,
                                                       csr_src, csr_norm);
  // combined h0 = [x_p ; x_np]
  {
    const int NT4 = N_TOT * C_DIM / 4;
    concat_kernel<<<(NT4 + 255) / 256, 256, 0, stream>>>(x_p, x_np, hA);
  }

  // --- 7 walk steps: GEMM then aggregate(+trace), h updated in place ---
  for (int t = 0; t < WALK; ++t) {
    gemm_kernel<<<N_TOT / BM, 256, 0, stream>>>(hA, W_gcn, xw);
    agg_kernel<<<N_TOT, 128, 0, stream>>>(xw, hA, ptr, csr_src, csr_norm, dinv,
                                          b_gcn, tr, t);
  }

  // --- standardize + MLP + sigmoid ---
  final_kernel<<<1, B_SZ, 0, stream>>>(tr, y, W1, b1, W2, b2, out);
}

// Round 3
// 1236.025 us; speedup vs baseline: 1.1307x; 1.1307x over previous
//
#include <hip/hip_runtime.h>
#include <math.h>

namespace {

constexpr int C_DIM  = 128;
constexpr int B_SZ   = 256;
constexpr int NP_OFF = 32768;         // np-graph node-id offset
constexpr int N_TOT  = 32896;         // 32768 + 128 combined rows
constexpr int E_P    = 524288;
constexpr int E_NP   = 2048;
constexpr int E_TOT  = E_P + E_NP;
constexpr int WALK   = 7;
constexpr int NTR    = 257;           // 256 p-block traces + 1 np trace

// ---------------- precompute ----------------

__global__ void init_kernel(int* __restrict__ cnt, float* __restrict__ tr) {
  int i = blockIdx.x * blockDim.x + threadIdx.x;
  if (i < N_TOT) cnt[i] = 0;
  if (i < WALK * NTR) tr[i] = 0.0f;
}

// NOTE: harness delivers integer inputs as int32 (even though reference uses int64)
__global__ void count_kernel(const int* __restrict__ ei_p,
                             const int* __restrict__ ei_np,
                             int* __restrict__ cnt) {
  int e = blockIdx.x * blockDim.x + threadIdx.x;
  if (e < E_P) {
    int d = ei_p[E_P + e];
    atomicAdd(&cnt[d], 1);
  } else if (e < E_TOT) {
    int i = e - E_P;
    int d = ei_np[E_NP + i] + NP_OFF;
    atomicAdd(&cnt[d], 1);
  }
}

__global__ void dinv_kernel(const int* __restrict__ cnt, float* __restrict__ dinv,
                            int* __restrict__ fill) {
  int i = blockIdx.x * blockDim.x + threadIdx.x;
  if (i < N_TOT) {
    dinv[i] = rsqrtf((float)cnt[i] + 1.0f);  // +1 self loop
    fill[i] = 0;
  }
}

// single-block hierarchical exclusive scan of cnt -> ptr (length N_TOT+1)
__global__ void scan_kernel(const int* __restrict__ cnt, int* __restrict__ ptr) {
  const int T = 1024;
  __shared__ int part[T];
  int tid = threadIdx.x;
  const int chunk = (N_TOT + T - 1) / T;
  int begin = tid * chunk;
  int end = begin + chunk;
  if (end > N_TOT) end = N_TOT;
  int s = 0;
  for (int i = begin; i < end; ++i) s += cnt[i];
  part[tid] = s;
  __syncthreads();
  for (int off = 1; off < T; off <<= 1) {
    int v = (tid >= off) ? part[tid - off] : 0;
    __syncthreads();
    part[tid] += v;
    __syncthreads();
  }
  if (tid == T - 1) ptr[N_TOT] = part[T - 1];
  int run = (tid == 0) ? 0 : part[tid - 1];
  for (int i = begin; i < end; ++i) { ptr[i] = run; run += cnt[i]; }
}

__global__ void fill_kernel(const int* __restrict__ ei_p,
                            const int* __restrict__ ei_np,
                            const int* __restrict__ ptr, int* __restrict__ fill,
                            const float* __restrict__ dinv,
                            int* __restrict__ csr_src, float* __restrict__ csr_norm) {
  int e = blockIdx.x * blockDim.x + threadIdx.x;
  int s, d;
  if (e < E_P) {
    s = ei_p[e];
    d = ei_p[E_P + e];
  } else if (e < E_TOT) {
    int i = e - E_P;
    s = ei_np[i] + NP_OFF;
    d = ei_np[E_NP + i] + NP_OFF;
  } else {
    return;
  }
  int pos = ptr[d] + atomicAdd(&fill[d], 1);
  csr_src[pos] = s;
  csr_norm[pos] = dinv[s] * dinv[d];
}

__global__ void concat_kernel(const float* __restrict__ x_p,
                              const float* __restrict__ x_np,
                              float* __restrict__ hA) {
  int i = blockIdx.x * blockDim.x + threadIdx.x;  // float4 index
  const int NP4 = NP_OFF * C_DIM / 4;
  const int NT4 = N_TOT * C_DIM / 4;
  if (i < NP4) {
    ((float4*)hA)[i] = ((const float4*)x_p)[i];
  } else if (i < NT4) {
    ((float4*)hA)[i] = ((const float4*)x_np)[i - NP4];
  }
}

// ---------------- per-step kernels ----------------

// xw[M x 128] = A[M x 128] @ W[128 x 128], fp32 (no fp32 MFMA on CDNA4)
// BM=64, BN=128, BK=16, 256 threads, 4x8 register tile per thread
constexpr int BM = 64;
constexpr int BK = 16;
constexpr int BN = 128;

__global__ __launch_bounds__(256) void gemm_kernel(const float* __restrict__ A,
                                                   const float* __restrict__ W,
                                                   float* __restrict__ Cm) {
  __shared__ float As[BK][BM];
  __shared__ float Bs[BK][BN];
  const int tid = threadIdx.x;
  const int row0 = blockIdx.x * BM;
  const int tx = tid & 15;        // n-tile index
  const int ty = tid >> 4;        // m-tile index
  const int m0 = ty * 4;
  const int n0 = tx * 8;
  const int a_row = tid >> 2;          // 0..63
  const int a_kc = (tid & 3) * 4;      // 0,4,8,12
  const int b_krow = tid >> 4;         // 0..15
  const int b_col = (tid & 15) * 8;    // 0..120

  float acc[4][8];
#pragma unroll
  for (int r = 0; r < 4; ++r)
#pragma unroll
    for (int c = 0; c < 8; ++c) acc[r][c] = 0.0f;

  for (int k0 = 0; k0 < C_DIM; k0 += BK) {
    float4 av = *(const float4*)&A[(size_t)(row0 + a_row) * C_DIM + k0 + a_kc];
    As[a_kc + 0][a_row] = av.x;
    As[a_kc + 1][a_row] = av.y;
    As[a_kc + 2][a_row] = av.z;
    As[a_kc + 3][a_row] = av.w;
    *(float4*)&Bs[b_krow][b_col] =
        *(const float4*)&W[(size_t)(k0 + b_krow) * C_DIM + b_col];
    *(float4*)&Bs[b_krow][b_col + 4] =
        *(const float4*)&W[(size_t)(k0 + b_krow) * C_DIM + b_col + 4];
    __syncthreads();
#pragma unroll
    for (int k = 0; k < BK; ++k) {
      float4 a4 = *(const float4*)&As[k][m0];
      float4 bL = *(const float4*)&Bs[k][n0];
      float4 bH = *(const float4*)&Bs[k][n0 + 4];
      float avr[4] = {a4.x, a4.y, a4.z, a4.w};
      float bvr[8] = {bL.x, bL.y, bL.z, bL.w, bH.x, bH.y, bH.z, bH.w};
#pragma unroll
      for (int r = 0; r < 4; ++r)
#pragma unroll
        for (int c = 0; c < 8; ++c) acc[r][c] += avr[r] * bvr[c];
    }
    __syncthreads();
  }

#pragma unroll
  for (int r = 0; r < 4; ++r) {
    float4 o0 = make_float4(acc[r][0], acc[r][1], acc[r][2], acc[r][3]);
    float4 o1 = make_float4(acc[r][4], acc[r][5], acc[r][6], acc[r][7]);
    *(float4*)&Cm[(size_t)(row0 + m0 + r) * C_DIM + n0] = o0;
    *(float4*)&Cm[(size_t)(row0 + m0 + r) * C_DIM + n0 + 4] = o1;
  }
}

// h_out[node][c] = b[c] + dinv[node]^2 * xw[node][c] + sum_e norm[e]*xw[src[e]][c]
// One WAVE per node. Lane layout: half = lane>>5 (parallel edge chain),
// c4 = lane&31 (float4 channel group). Each half-chain is unrolled x2 ->
// up to 4 independent 16B gathers in flight per lane (latency hiding; the
// R2 profile showed VALUBusy=3%, hbm=11% -> pure latency-bound serial loop).
__global__ __launch_bounds__(256) void agg_kernel(const float* __restrict__ xw,
                                                  float* __restrict__ hout,
                                                  const int* __restrict__ ptr,
                                                  const int* __restrict__ srcs,
                                                  const float* __restrict__ norms,
                                                  const float* __restrict__ dinv,
                                                  const float* __restrict__ bias,
                                                  float* __restrict__ tr, int step) {
  const int wave = threadIdx.x >> 6;                 // 0..3
  const int lane = threadIdx.x & 63;
  const int half = lane >> 5;                        // 0,1: edge chain id
  const int c4   = lane & 31;                        // float4 channel group
  const int node = blockIdx.x * 4 + wave;            // grid is exact (32896/4)

  const int e0 = ptr[node];
  const int e1 = ptr[node + 1];
  const float4* __restrict__ xw4 = (const float4*)xw;

  float4 acc = make_float4(0.f, 0.f, 0.f, 0.f);
  int e = e0 + half;
  // unrolled x2: chains e, e+2 (stride 4 per iteration)
  for (; e + 2 < e1; e += 4) {
    int   s0 = srcs[e],     s1 = srcs[e + 2];
    float n0 = norms[e],    n1 = norms[e + 2];
    float4 r0 = xw4[(size_t)s0 * 32 + c4];
    float4 r1 = xw4[(size_t)s1 * 32 + c4];
    acc.x += n0 * r0.x + n1 * r1.x;
    acc.y += n0 * r0.y + n1 * r1.y;
    acc.z += n0 * r0.z + n1 * r1.z;
    acc.w += n0 * r0.w + n1 * r1.w;
  }
  for (; e < e1; e += 2) {
    int   s = srcs[e];
    float nv = norms[e];
    float4 r = xw4[(size_t)s * 32 + c4];
    acc.x += nv * r.x;
    acc.y += nv * r.y;
    acc.z += nv * r.z;
    acc.w += nv * r.w;
  }

  // combine the two half-chains (lane i <-> lane i+32)
  acc.x += __shfl_xor(acc.x, 32);
  acc.y += __shfl_xor(acc.y, 32);
  acc.z += __shfl_xor(acc.z, 32);
  acc.w += __shfl_xor(acc.w, 32);

  const float di = dinv[node];
  const float dd = di * di;
  float4 self = xw4[(size_t)node * 32 + c4];
  float4 bb = ((const float4*)bias)[c4];
  float4 outv;
  outv.x = bb.x + dd * self.x + acc.x;
  outv.y = bb.y + dd * self.y + acc.y;
  outv.z = bb.z + dd * self.z + acc.z;
  outv.w = bb.w + dd * self.w + acc.w;

  if (half == 0) {
    ((float4*)hout)[(size_t)node * 32 + c4] = outv;
    const int dcol = node & 127;                      // diagonal column
    if (c4 == (dcol >> 2)) {
      float dval = (&outv.x)[dcol & 3];
      atomicAdd(&tr[step * NTR + (node >> 7)], dval);
    }
  }
}

// ---------------- epilogue ----------------

__global__ __launch_bounds__(256) void final_kernel(const float* __restrict__ tr,
                                                    const float* __restrict__ y,
                                                    const float* __restrict__ W1,
                                                    const float* __restrict__ b1,
                                                    const float* __restrict__ W2,
                                                    const float* __restrict__ b2,
                                                    float* __restrict__ out) {
  __shared__ float sm[B_SZ];
  const int b = threadIdx.x;
  const float sgn = (y[b] - 0.5f) * 2.0f;
  float vals[WALK];
#pragma unroll
  for (int t = 0; t < WALK; ++t)
    vals[t] = (tr[t * NTR + b] - tr[t * NTR + 256]) * sgn;

  for (int t = 0; t < WALK; ++t) {
    sm[b] = vals[t];
    __syncthreads();
    for (int off = 128; off >= 1; off >>= 1) {
      if (b < off) sm[b] += sm[b + off];
      __syncthreads();
    }
    float mean = sm[0] * (1.0f / 256.0f);
    __syncthreads();
    float d = vals[t] - mean;
    sm[b] = d * d;
    __syncthreads();
    for (int off = 128; off >= 1; off >>= 1) {
      if (b < off) sm[b] += sm[b + off];
      __syncthreads();
    }
    float stdv = sqrtf(sm[0] * (1.0f / 255.0f));  // ddof=1
    __syncthreads();
    vals[t] = d / stdv;
  }

  float o = b2[0];
#pragma unroll
  for (int j = 0; j < 15; ++j) {
    float a = b1[j];
#pragma unroll
    for (int t = 0; t < WALK; ++t) a += vals[t] * W1[t * 15 + j];
    o += fmaxf(a, 0.0f) * W2[j];
  }
  out[b] = 1.0f / (1.0f + expf(-o));
}

}  // namespace

extern "C" void kernel_launch(void* const* d_in, const int* in_sizes, int n_in,
                              void* d_out, int out_size, void* d_ws, size_t ws_size,
                              hipStream_t stream) {
  const float* x_p   = (const float*)d_in[0];
  const float* x_np  = (const float*)d_in[1];
  const float* y     = (const float*)d_in[2];
  const int* ei_p    = (const int*)d_in[3];   // int inputs arrive as int32
  const int* ei_np   = (const int*)d_in[4];
  const float* W_gcn = (const float*)d_in[5];
  const float* b_gcn = (const float*)d_in[6];
  const float* W1    = (const float*)d_in[7];
  const float* b1    = (const float*)d_in[8];
  const float* W2    = (const float*)d_in[9];
  const float* b2    = (const float*)d_in[10];
  float* out         = (float*)d_out;

  // bump allocator over d_ws (re-poisoned to 0xAA each call; we init all we read)
  char* p = (char*)d_ws;
  auto alloc = [&](size_t bytes) -> void* {
    void* r = (void*)p;
    p += (bytes + 255) & ~(size_t)255;
    return r;
  };
  float* hA       = (float*)alloc((size_t)N_TOT * C_DIM * 4);  // h (in-place per step)
  float* xw       = (float*)alloc((size_t)N_TOT * C_DIM * 4);  // h @ W
  float* dinv     = (float*)alloc((size_t)N_TOT * 4);
  int*   cnt      = (int*)alloc((size_t)N_TOT * 4);
  int*   fill     = (int*)alloc((size_t)N_TOT * 4);
  int*   ptr      = (int*)alloc((size_t)(N_TOT + 1) * 4);
  int*   csr_src  = (int*)alloc((size_t)E_TOT * 4);
  float* csr_norm = (float*)alloc((size_t)E_TOT * 4);
  float* tr       = (float*)alloc((size_t)WALK * NTR * 4);

  // --- precompute: degrees, norms, CSR (edges invariant across the 7 steps) ---
  init_kernel<<<(N_TOT + 255) / 256, 256, 0, stream>>>(cnt, tr);
  count_kernel<<<(E_TOT + 255) / 256, 256, 0, stream>>>(ei_p, ei_np, cnt);
  dinv_kernel<<<(N_TOT + 255) / 256, 256, 0, stream>>>(cnt, dinv, fill);
  scan_kernel<<<1, 1024, 0, stream>>>(cnt, ptr);
  fill_kernel<<<(E_TOT + 255) / 256, 256, 0, stream>>>(ei_p, ei_np, ptr, fill, dinv,
                                                       csr_src, csr_norm);
  // combined h0 = [x_p ; x_np]
  {
    const int NT4 = N_TOT * C_DIM / 4;
    concat_kernel<<<(NT4 + 255) / 256, 256, 0, stream>>>(x_p, x_np, hA);
  }

  // --- 7 walk steps: GEMM then aggregate(+trace), h updated in place ---
  for (int t = 0; t < WALK; ++t) {
    gemm_kernel<<<N_TOT / BM, 256, 0, stream>>>(hA, W_gcn, xw);
    agg_kernel<<<N_TOT / 4, 256, 0, stream>>>(xw, hA, ptr, csr_src, csr_norm, dinv,
                                              b_gcn, tr, t);
  }

  // --- standardize + MLP + sigmoid ---
  final_kernel<<<1, B_SZ, 0, stream>>>(tr, y, W1, b1, W2, b2, out);
}

// Round 4
// 1019.630 us; speedup vs baseline: 1.3707x; 1.2122x over previous
//
#include <hip/hip_runtime.h>
#include <hip/hip_bf16.h>
#include <math.h>

namespace {

constexpr int C_DIM  = 128;
constexpr int B_SZ   = 256;
constexpr int NP_OFF = 32768;         // np-graph node-id offset
constexpr int N_TOT  = 32896;         // 32768 + 128 combined rows
constexpr int E_P    = 524288;
constexpr int E_NP   = 2048;
constexpr int E_TOT  = E_P + E_NP;
constexpr int WALK   = 7;
constexpr int NTR    = 257;           // 256 p-block traces + 1 np trace

typedef short bf16x8 __attribute__((ext_vector_type(8)));
typedef float f32x4 __attribute__((ext_vector_type(4)));

__device__ __forceinline__ float bfu(unsigned short u) {
  return __uint_as_float(((unsigned int)u) << 16);
}

// ---------------- precompute ----------------

__global__ void init_kernel(int* __restrict__ cnt, float* __restrict__ tr) {
  int i = blockIdx.x * blockDim.x + threadIdx.x;
  if (i < N_TOT) cnt[i] = 0;
  if (i < WALK * NTR) tr[i] = 0.0f;
}

// NOTE: harness delivers integer inputs as int32
__global__ void count_kernel(const int* __restrict__ ei_p,
                             const int* __restrict__ ei_np,
                             int* __restrict__ cnt) {
  int e = blockIdx.x * blockDim.x + threadIdx.x;
  if (e < E_P) {
    int d = ei_p[E_P + e];
    atomicAdd(&cnt[d], 1);
  } else if (e < E_TOT) {
    int i = e - E_P;
    int d = ei_np[E_NP + i] + NP_OFF;
    atomicAdd(&cnt[d], 1);
  }
}

__global__ void dinv_kernel(const int* __restrict__ cnt, float* __restrict__ dinv,
                            int* __restrict__ fill) {
  int i = blockIdx.x * blockDim.x + threadIdx.x;
  if (i < N_TOT) {
    dinv[i] = rsqrtf((float)cnt[i] + 1.0f);  // +1 self loop
    fill[i] = 0;
  }
}

// single-block hierarchical exclusive scan of cnt -> ptr (length N_TOT+1)
__global__ void scan_kernel(const int* __restrict__ cnt, int* __restrict__ ptr) {
  const int T = 1024;
  __shared__ int part[T];
  int tid = threadIdx.x;
  const int chunk = (N_TOT + T - 1) / T;
  int begin = tid * chunk;
  int end = begin + chunk;
  if (end > N_TOT) end = N_TOT;
  int s = 0;
  for (int i = begin; i < end; ++i) s += cnt[i];
  part[tid] = s;
  __syncthreads();
  for (int off = 1; off < T; off <<= 1) {
    int v = (tid >= off) ? part[tid - off] : 0;
    __syncthreads();
    part[tid] += v;
    __syncthreads();
  }
  if (tid == T - 1) ptr[N_TOT] = part[T - 1];
  int run = (tid == 0) ? 0 : part[tid - 1];
  for (int i = begin; i < end; ++i) { ptr[i] = run; run += cnt[i]; }
}

__global__ void fill_kernel(const int* __restrict__ ei_p,
                            const int* __restrict__ ei_np,
                            const int* __restrict__ ptr, int* __restrict__ fill,
                            const float* __restrict__ dinv,
                            int* __restrict__ csr_src, float* __restrict__ csr_norm) {
  int e = blockIdx.x * blockDim.x + threadIdx.x;
  int s, d;
  if (e < E_P) {
    s = ei_p[e];
    d = ei_p[E_P + e];
  } else if (e < E_TOT) {
    int i = e - E_P;
    s = ei_np[i] + NP_OFF;
    d = ei_np[E_NP + i] + NP_OFF;
  } else {
    return;
  }
  int pos = ptr[d] + atomicAdd(&fill[d], 1);
  csr_src[pos] = s;
  csr_norm[pos] = dinv[s] * dinv[d];
}

// h0 = round_bf16([x_p ; x_np]); thread handles 8 floats -> one 16B bf16 store
__global__ void concat_kernel(const float* __restrict__ x_p,
                              const float* __restrict__ x_np,
                              __hip_bfloat16* __restrict__ hb) {
  int i = blockIdx.x * blockDim.x + threadIdx.x;  // 8-elem chunk index
  const int NP8 = NP_OFF * C_DIM / 8;
  const int NT8 = N_TOT * C_DIM / 8;
  if (i >= NT8) return;
  const float* src = (i < NP8) ? (x_p + (size_t)i * 8)
                               : (x_np + (size_t)(i - NP8) * 8);
  union { __hip_bfloat16 h[8]; uint4 u; } pk;
#pragma unroll
  for (int j = 0; j < 8; ++j) pk.h[j] = __float2bfloat16(src[j]);
  ((uint4*)hb)[i] = pk.u;
}

// Wt[n][k] = bf16(W[k][n])  (128x128, trivial)
__global__ void wtrans_kernel(const float* __restrict__ W,
                              __hip_bfloat16* __restrict__ Wt) {
  int i = blockIdx.x * blockDim.x + threadIdx.x;
  if (i >= C_DIM * C_DIM) return;
  int n = i & 127, k = i >> 7;
  Wt[n * C_DIM + k] = __float2bfloat16(W[i]);
}

// ---------------- per-step kernels ----------------

// xw = h @ W via MFMA bf16. Block = 4 waves, wave handles 16 rows x 128 cols.
// A-frag: lane holds A[m=lane&15][k=kc*32 + (lane>>4)*8 + j]; B from Wt rows.
__global__ __launch_bounds__(256) void gemm_kernel(const __hip_bfloat16* __restrict__ hb,
                                                   const __hip_bfloat16* __restrict__ Wt,
                                                   __hip_bfloat16* __restrict__ xwb) {
  const int wave = threadIdx.x >> 6;
  const int lane = threadIdx.x & 63;
  const int q = lane >> 4;
  const int l16 = lane & 15;
  const int m_base = blockIdx.x * 64 + wave * 16;
  const int m = m_base + l16;

  bf16x8 a[4];
#pragma unroll
  for (int kc = 0; kc < 4; ++kc)
    a[kc] = *(const bf16x8*)(hb + (size_t)m * C_DIM + kc * 32 + q * 8);

#pragma unroll
  for (int j = 0; j < 8; ++j) {
    const int n = j * 16 + l16;
    f32x4 acc = {0.f, 0.f, 0.f, 0.f};
#pragma unroll
    for (int kc = 0; kc < 4; ++kc) {
      bf16x8 b = *(const bf16x8*)(Wt + (size_t)n * C_DIM + kc * 32 + q * 8);
      acc = __builtin_amdgcn_mfma_f32_16x16x32_bf16(a[kc], b, acc, 0, 0, 0);
    }
    // D: col = lane&15 (= n), row = q*4 + r
#pragma unroll
    for (int r = 0; r < 4; ++r)
      xwb[(size_t)(m_base + q * 4 + r) * C_DIM + n] = __float2bfloat16(acc[r]);
  }
}

// h_out[node][c] = b[c] + dinv^2*xw[node][c] + sum_e norm[e]*xw[src[e]][c]
// One wave per node; 4 parallel edge chains (quarter = lane>>4), each lane
// loads 16B = 8 bf16 channels; unroll x2 -> 8 independent gathers in flight.
__global__ __launch_bounds__(256) void agg_kernel(const __hip_bfloat16* __restrict__ xwb,
                                                  __hip_bfloat16* __restrict__ hb,
                                                  const int* __restrict__ ptr,
                                                  const int* __restrict__ srcs,
                                                  const float* __restrict__ norms,
                                                  const float* __restrict__ dinv,
                                                  const float* __restrict__ bias,
                                                  float* __restrict__ tr, int step) {
  const int wave = threadIdx.x >> 6;
  const int lane = threadIdx.x & 63;
  const int q   = lane >> 4;     // edge-chain id (0..3)
  const int c8  = lane & 15;     // 8-channel group
  const int node = blockIdx.x * 4 + wave;

  const int e0 = ptr[node];
  const int e1 = ptr[node + 1];
  const uint4* __restrict__ xw16 = (const uint4*)xwb;  // 16 uint4 per row

  float acc[8];
#pragma unroll
  for (int i = 0; i < 8; ++i) acc[i] = 0.f;

  int e = e0 + q;
  for (; e + 4 < e1; e += 8) {
    int   s0 = srcs[e],  s1 = srcs[e + 4];
    float n0 = norms[e], n1 = norms[e + 4];
    uint4 r0 = xw16[(size_t)s0 * 16 + c8];
    uint4 r1 = xw16[(size_t)s1 * 16 + c8];
    unsigned int w0[4] = {r0.x, r0.y, r0.z, r0.w};
    unsigned int w1[4] = {r1.x, r1.y, r1.z, r1.w};
#pragma unroll
    for (int i = 0; i < 4; ++i) {
      acc[2 * i]     += n0 * __uint_as_float(w0[i] << 16)
                      + n1 * __uint_as_float(w1[i] << 16);
      acc[2 * i + 1] += n0 * __uint_as_float(w0[i] & 0xffff0000u)
                      + n1 * __uint_as_float(w1[i] & 0xffff0000u);
    }
  }
  for (; e < e1; e += 4) {
    int   s = srcs[e];
    float nv = norms[e];
    uint4 r = xw16[(size_t)s * 16 + c8];
    unsigned int w[4] = {r.x, r.y, r.z, r.w};
#pragma unroll
    for (int i = 0; i < 4; ++i) {
      acc[2 * i]     += nv * __uint_as_float(w[i] << 16);
      acc[2 * i + 1] += nv * __uint_as_float(w[i] & 0xffff0000u);
    }
  }

  // combine the 4 chains (quarters)
#pragma unroll
  for (int i = 0; i < 8; ++i) {
    acc[i] += __shfl_xor(acc[i], 16);
    acc[i] += __shfl_xor(acc[i], 32);
  }

  if (q == 0) {
    const float di = dinv[node];
    const float dd = di * di;
    uint4 sr = xw16[(size_t)node * 16 + c8];
    unsigned int sw[4] = {sr.x, sr.y, sr.z, sr.w};
    float4 b0 = ((const float4*)bias)[c8 * 2];
    float4 b1 = ((const float4*)bias)[c8 * 2 + 1];
    float bb[8] = {b0.x, b0.y, b0.z, b0.w, b1.x, b1.y, b1.z, b1.w};
    float outv[8];
#pragma unroll
    for (int i = 0; i < 4; ++i) {
      outv[2 * i]     = bb[2 * i]     + dd * __uint_as_float(sw[i] << 16)        + acc[2 * i];
      outv[2 * i + 1] = bb[2 * i + 1] + dd * __uint_as_float(sw[i] & 0xffff0000u) + acc[2 * i + 1];
    }
    union { __hip_bfloat16 h[8]; uint4 u; } pk;
#pragma unroll
    for (int i = 0; i < 8; ++i) pk.h[i] = __float2bfloat16(outv[i]);
    ((uint4*)hb)[(size_t)node * 16 + c8] = pk.u;

    const int dcol = node & 127;
    if (c8 == (dcol >> 3)) {
      atomicAdd(&tr[step * NTR + (node >> 7)], outv[dcol & 7]);
    }
  }
}

// Last walk step: only the diagonal of h is needed (traces). Per-node scalar
// gather of a single channel.
__global__ __launch_bounds__(256) void trace_kernel(const __hip_bfloat16* __restrict__ xwb,
                                                    const int* __restrict__ ptr,
                                                    const int* __restrict__ srcs,
                                                    const float* __restrict__ norms,
                                                    const float* __restrict__ dinv,
                                                    const float* __restrict__ bias,
                                                    float* __restrict__ tr, int step) {
  int node = blockIdx.x * blockDim.x + threadIdx.x;
  if (node >= N_TOT) return;
  const unsigned short* xu = (const unsigned short*)xwb;
  const int dcol = node & 127;
  const float di = dinv[node];
  float acc = bias[dcol] + di * di * bfu(xu[(size_t)node * C_DIM + dcol]);
  const int e1 = ptr[node + 1];
  for (int e = ptr[node]; e < e1; ++e)
    acc += norms[e] * bfu(xu[(size_t)srcs[e] * C_DIM + dcol]);
  atomicAdd(&tr[step * NTR + (node >> 7)], acc);
}

// ---------------- epilogue ----------------

__global__ __launch_bounds__(256) void final_kernel(const float* __restrict__ tr,
                                                    const float* __restrict__ y,
                                                    const float* __restrict__ W1,
                                                    const float* __restrict__ b1,
                                                    const float* __restrict__ W2,
                                                    const float* __restrict__ b2,
                                                    float* __restrict__ out) {
  __shared__ float sm[B_SZ];
  const int b = threadIdx.x;
  const float sgn = (y[b] - 0.5f) * 2.0f;
  float vals[WALK];
#pragma unroll
  for (int t = 0; t < WALK; ++t)
    vals[t] = (tr[t * NTR + b] - tr[t * NTR + 256]) * sgn;

  for (int t = 0; t < WALK; ++t) {
    sm[b] = vals[t];
    __syncthreads();
    for (int off = 128; off >= 1; off >>= 1) {
      if (b < off) sm[b] += sm[b + off];
      __syncthreads();
    }
    float mean = sm[0] * (1.0f / 256.0f);
    __syncthreads();
    float d = vals[t] - mean;
    sm[b] = d * d;
    __syncthreads();
    for (int off = 128; off >= 1; off >>= 1) {
      if (b < off) sm[b] += sm[b + off];
      __syncthreads();
    }
    float stdv = sqrtf(sm[0] * (1.0f / 255.0f));  // ddof=1
    __syncthreads();
    vals[t] = d / stdv;
  }

  float o = b2[0];
#pragma unroll
  for (int j = 0; j < 15; ++j) {
    float a = b1[j];
#pragma unroll
    for (int t = 0; t < WALK; ++t) a += vals[t] * W1[t * 15 + j];
    o += fmaxf(a, 0.0f) * W2[j];
  }
  out[b] = 1.0f / (1.0f + expf(-o));
}

}  // namespace

extern "C" void kernel_launch(void* const* d_in, const int* in_sizes, int n_in,
                              void* d_out, int out_size, void* d_ws, size_t ws_size,
                              hipStream_t stream) {
  const float* x_p   = (const float*)d_in[0];
  const float* x_np  = (const float*)d_in[1];
  const float* y     = (const float*)d_in[2];
  const int* ei_p    = (const int*)d_in[3];   // int inputs arrive as int32
  const int* ei_np   = (const int*)d_in[4];
  const float* W_gcn = (const float*)d_in[5];
  const float* b_gcn = (const float*)d_in[6];
  const float* W1    = (const float*)d_in[7];
  const float* b1    = (const float*)d_in[8];
  const float* W2    = (const float*)d_in[9];
  const float* b2    = (const float*)d_in[10];
  float* out         = (float*)d_out;

  char* p = (char*)d_ws;
  auto alloc = [&](size_t bytes) -> void* {
    void* r = (void*)p;
    p += (bytes + 255) & ~(size_t)255;
    return r;
  };
  __hip_bfloat16* hb  = (__hip_bfloat16*)alloc((size_t)N_TOT * C_DIM * 2);  // h (bf16)
  __hip_bfloat16* xwb = (__hip_bfloat16*)alloc((size_t)N_TOT * C_DIM * 2);  // h @ W (bf16)
  __hip_bfloat16* Wt  = (__hip_bfloat16*)alloc((size_t)C_DIM * C_DIM * 2);  // W^T bf16
  float* dinv     = (float*)alloc((size_t)N_TOT * 4);
  int*   cnt      = (int*)alloc((size_t)N_TOT * 4);
  int*   fill     = (int*)alloc((size_t)N_TOT * 4);
  int*   ptr      = (int*)alloc((size_t)(N_TOT + 1) * 4);
  int*   csr_src  = (int*)alloc((size_t)E_TOT * 4);
  float* csr_norm = (float*)alloc((size_t)E_TOT * 4);
  float* tr       = (float*)alloc((size_t)WALK * NTR * 4);

  // --- precompute ---
  init_kernel<<<(N_TOT + 255) / 256, 256, 0, stream>>>(cnt, tr);
  count_kernel<<<(E_TOT + 255) / 256, 256, 0, stream>>>(ei_p, ei_np, cnt);
  dinv_kernel<<<(N_TOT + 255) / 256, 256, 0, stream>>>(cnt, dinv, fill);
  scan_kernel<<<1, 1024, 0, stream>>>(cnt, ptr);
  fill_kernel<<<(E_TOT + 255) / 256, 256, 0, stream>>>(ei_p, ei_np, ptr, fill, dinv,
                                                       csr_src, csr_norm);
  wtrans_kernel<<<(C_DIM * C_DIM + 255) / 256, 256, 0, stream>>>(W_gcn, Wt);
  {
    const int NT8 = N_TOT * C_DIM / 8;
    concat_kernel<<<(NT8 + 255) / 256, 256, 0, stream>>>(x_p, x_np, hb);
  }

  // --- 7 walk steps ---
  for (int t = 0; t < WALK; ++t) {
    gemm_kernel<<<N_TOT / 64, 256, 0, stream>>>(hb, Wt, xwb);
    if (t < WALK - 1) {
      agg_kernel<<<N_TOT / 4, 256, 0, stream>>>(xwb, hb, ptr, csr_src, csr_norm,
                                                dinv, b_gcn, tr, t);
    } else {
      trace_kernel<<<(N_TOT + 255) / 256, 256, 0, stream>>>(xwb, ptr, csr_src,
                                                            csr_norm, dinv, b_gcn,
                                                            tr, t);
    }
  }

  // --- standardize + MLP + sigmoid ---
  final_kernel<<<1, B_SZ, 0, stream>>>(tr, y, W1, b1, W2, b2, out);
}